// Round 11
// baseline (151.355 us; speedup 1.0000x reference)
//
#include <hip/hip_runtime.h>

// CrossHeadProjectionV2: B=1, N=16, T=S=2048, G=1, I=2, M=16.
// out[n,t,s] = sum_m x[m,t,s]*wq[t][m][n]
//            + sum_i kw2[s,i,n] * (sum_m x[m,t,s]*kw1[s,i,m])
//            + x[n,t,s]*kdd[s,n]
//
// R11: occupancy A/B at FIXED traffic. R10 proved the cap is the unified
// register file (84 VGPR + ~80 AGPR pinned kt = 168/thread -> 2.3 waves/SIMD).
// Split ownership to 2 rows/lane (8 j-slots x 8 quads per wave), 512-thread
// blocks: kt 80->40 floats, acc 16->8, xp 16->8 => ~100 regs -> 4+ waves/SIMD.
// SBLK=256, TT=8, grid 2048, same chunk sizes, same bytes as R8.

#define TDIM 2048
#define SDIM 2048
#define TT 8
#define SBLK 256
#define THREADS 512

typedef float vf4 __attribute__((ext_vector_type(4)));

__device__ __forceinline__ void barrier_nodrain() {
  asm volatile("s_waitcnt lgkmcnt(0)" ::: "memory");
  __builtin_amdgcn_s_barrier();
  asm volatile("" ::: "memory");
}

// Opaque pin: keeps loaded weights register-resident (R8: ~7% win).
__device__ __forceinline__ void pin4(vf4& v) {
  float a = v.x, b = v.y, c = v.z, d = v.w;
  asm volatile("" : "+v"(a), "+v"(b), "+v"(c), "+v"(d));
  v.x = a; v.y = b; v.z = c; v.w = d;
}

// ---- prep: transpose per-s weights to s-minor for coalesced reads ----
__global__ void chp_prep(const float* __restrict__ kw1, const float* __restrict__ kw2,
                         const float* __restrict__ kdd,
                         float* __restrict__ kt1, float* __restrict__ kt2,
                         float* __restrict__ kddt) {
  int tid = blockIdx.x * blockDim.x + threadIdx.x;  // 0 .. 163839
  if (tid < 65536) {
    int im = tid >> 11, s = tid & 2047;
    kt1[tid] = kw1[s * 32 + im];
  } else if (tid < 131072) {
    int v = tid - 65536;
    int im = v >> 11, s = v & 2047;
    kt2[v] = kw2[s * 32 + im];
  } else if (tid < 163840) {
    int v = tid - 131072;
    int n = v >> 11, s = v & 2047;
    kddt[v] = kdd[s * 16 + n];
  }
}

__device__ __forceinline__ vf4 ld4(const float* p) {
  return *reinterpret_cast<const vf4*>(p);
}
__device__ __forceinline__ void fma4(vf4& d, const vf4& a, const vf4& b) {
  d.x = fmaf(a.x, b.x, d.x); d.y = fmaf(a.y, b.y, d.y);
  d.z = fmaf(a.z, b.z, d.z); d.w = fmaf(a.w, b.w, d.w);
}
__device__ __forceinline__ void fma4s(vf4& d, const vf4& a, float b) {
  d.x = fmaf(a.x, b, d.x); d.y = fmaf(a.y, b, d.y);
  d.z = fmaf(a.z, b, d.z); d.w = fmaf(a.w, b, d.w);
}

template <bool KT>
__global__ __launch_bounds__(THREADS, 4) void chp_main(
    const float* __restrict__ in, const float* __restrict__ w,
    const float* __restrict__ qw1, const float* __restrict__ qw2,
    const float* __restrict__ qdd, const float* __restrict__ kw1,
    const float* __restrict__ kw2, const float* __restrict__ kdd,
    const float* __restrict__ kt1, const float* __restrict__ kt2,
    const float* __restrict__ kddt, float* __restrict__ out) {
  // x_lds[buf][m][quad], rows padded to 65 quads.
  __shared__ vf4 x_lds[2][16][65];
  __shared__ float wq_lds[2][256];

  const int tid = threadIdx.x;
  const int wv = tid >> 6;
  const int lane = tid & 63;
  const int j = lane & 7;        // owns rows {2j, 2j+1}
  const int qg = lane >> 3;      // quad within wave: 0..7
  const int quad = wv * 8 + qg;  // quad within block: 0..63
  const int s0 = blockIdx.x * SBLK + quad * 4;
  const int t0 = blockIdx.y * TT;

  // ---- per-thread register weights (own 2 rows, own s-quad), loaded ONCE ----
  vf4 kt1v[2][2], kt2v[2][2], kdv[2];
  if constexpr (KT) {
#pragma unroll
    for (int i = 0; i < 2; ++i)
#pragma unroll
      for (int k = 0; k < 2; ++k) {
        kt1v[i][k] = ld4(kt1 + (size_t)(i * 16 + 2 * j + k) * SDIM + s0);
        kt2v[i][k] = ld4(kt2 + (size_t)(i * 16 + 2 * j + k) * SDIM + s0);
      }
#pragma unroll
    for (int k = 0; k < 2; ++k) kdv[k] = ld4(kddt + (size_t)(2 * j + k) * SDIM + s0);
  } else {
#pragma unroll
    for (int i = 0; i < 2; ++i)
#pragma unroll
      for (int k = 0; k < 2; ++k)
#pragma unroll
        for (int c = 0; c < 4; ++c) {
          kt1v[i][k][c] = kw1[(size_t)(s0 + c) * 32 + i * 16 + 2 * j + k];
          kt2v[i][k][c] = kw2[(size_t)(s0 + c) * 32 + i * 16 + 2 * j + k];
        }
#pragma unroll
    for (int k = 0; k < 2; ++k)
#pragma unroll
      for (int c = 0; c < 4; ++c) kdv[k][c] = kdd[(size_t)(s0 + c) * 16 + 2 * j + k];
  }
#pragma unroll
  for (int i = 0; i < 2; ++i)
#pragma unroll
    for (int k = 0; k < 2; ++k) { pin4(kt1v[i][k]); pin4(kt2v[i][k]); }
#pragma unroll
  for (int k = 0; k < 2; ++k) pin4(kdv[k]);

  // wq-build: waves 0-3 (tid<256) build the 256 entries; wave-uniform branch.
  const bool builder = (tid < 256);
  const int bm = (tid >> 4) & 15, bn = tid & 15;
  const float wbase = builder ? w[bm * 16 + bn] : 0.0f;

  vf4 xp[2];
  float q1a = 0.f, q1b = 0.f, q2a = 0.f, q2b = 0.f, qd = 0.f;

  auto prefetch = [&](int t) {
#pragma unroll
    for (int k = 0; k < 2; ++k)
      xp[k] = ld4(in + ((size_t)(2 * j + k) * TDIM + t) * SDIM + s0);
    if (builder) {
      q1a = qw1[t * 32 + bm];
      q1b = qw1[t * 32 + 16 + bm];
      q2a = qw2[t * 32 + bn];
      q2b = qw2[t * 32 + 16 + bn];
      qd = qdd[t * 16 + bn];
    }
  };
  auto stage = [&](int buf) {
#pragma unroll
    for (int k = 0; k < 2; ++k) x_lds[buf][2 * j + k][quad] = xp[k];
    if (builder) {
      float v = fmaf(q1a, q2a, fmaf(q1b, q2b, wbase));
      if (bm == bn) v += 1.0f + qd;
      wq_lds[buf][tid] = v;
    }
  };

  // ---- prologue: prefetch + stage t0, prefetch t0+1 ----
  prefetch(t0);
  stage(0);
  prefetch(t0 + 1);
  barrier_nodrain();

  int cur = 0;
  for (int tt = 0; tt < TT; ++tt) {
    const int t = t0 + tt;
    const int nxt = cur ^ 1;

    // ---- compute t from LDS buf[cur] ----
    vf4 acc[2];
    vf4 p0 = (vf4){0.f, 0.f, 0.f, 0.f}, p1 = p0;
    acc[0] = (vf4){0.f, 0.f, 0.f, 0.f};
    acc[1] = (vf4){0.f, 0.f, 0.f, 0.f};

#pragma unroll
    for (int m = 0; m < 16; ++m) {
      const vf4 xm = x_lds[cur][m][quad];
      const float* wp = &wq_lds[cur][m * 16 + 2 * j];
      fma4s(acc[0], xm, wp[0]);
      fma4s(acc[1], xm, wp[1]);
      if ((m >> 1) == j) {  // own rows: hk partials + k-diag
        const int k = m & 1;
        fma4(p0, xm, kt1v[0][k]);
        fma4(p1, xm, kt1v[1][k]);
        fma4(acc[k], xm, kdv[k]);
      }
    }
    // butterfly over the 8 j-lanes (same qg): full hk at every lane
#pragma unroll
    for (int mask = 1; mask <= 4; mask <<= 1) {
      p0.x += __shfl_xor(p0.x, mask); p0.y += __shfl_xor(p0.y, mask);
      p0.z += __shfl_xor(p0.z, mask); p0.w += __shfl_xor(p0.w, mask);
      p1.x += __shfl_xor(p1.x, mask); p1.y += __shfl_xor(p1.y, mask);
      p1.z += __shfl_xor(p1.z, mask); p1.w += __shfl_xor(p1.w, mask);
    }
    // epilogue + stores
#pragma unroll
    for (int r = 0; r < 2; ++r) {
      fma4(acc[r], p0, kt2v[0][r]);
      fma4(acc[r], p1, kt2v[1][r]);
      *reinterpret_cast<vf4*>(out + ((size_t)(2 * j + r) * TDIM + t) * SDIM + s0) =
          acc[r];
    }

    // ---- stage t+1 into buf[nxt], then prefetch t+2 ----
    if (tt + 1 < TT) {
      stage(nxt);
      if (tt + 2 < TT) prefetch(t + 2);
    }
    // DS handoff drained; global prefetch stays in flight.
    barrier_nodrain();
    cur = nxt;
  }
}

extern "C" void kernel_launch(void* const* d_in, const int* in_sizes, int n_in,
                              void* d_out, int out_size, void* d_ws, size_t ws_size,
                              hipStream_t stream) {
  const float* in = (const float*)d_in[0];
  const float* qw1 = (const float*)d_in[1];
  const float* qw2 = (const float*)d_in[2];
  const float* kw1 = (const float*)d_in[3];
  const float* kw2 = (const float*)d_in[4];
  const float* qdd = (const float*)d_in[5];
  const float* kdd = (const float*)d_in[6];
  const float* w = (const float*)d_in[7];
  float* out = (float*)d_out;
  float* ws = (float*)d_ws;

  const bool useKT = (ws_size >= 163840ull * sizeof(float));
  float* kt1 = ws;
  float* kt2 = ws + 65536;
  float* kddt = ws + 131072;

  dim3 grid(SDIM / SBLK, TDIM / TT);  // (8, 256) = 2048 blocks
  if (useKT) {
    hipLaunchKernelGGL(chp_prep, dim3(640), dim3(256), 0, stream, kw1, kw2, kdd, kt1,
                       kt2, kddt);
    hipLaunchKernelGGL((chp_main<true>), grid, dim3(THREADS), 0, stream, in, w, qw1,
                       qw2, qdd, kw1, kw2, kdd, kt1, kt2, kddt, out);
  } else {
    hipLaunchKernelGGL((chp_main<false>), grid, dim3(THREADS), 0, stream, in, w, qw1,
                       qw2, qdd, kw1, kw2, kdd, nullptr, nullptr, nullptr, out);
  }
}

// Round 12
// 140.432 us; speedup vs baseline: 1.0778x; 1.0778x over previous
//
#include <hip/hip_runtime.h>

// CrossHeadProjectionV2: B=1, N=16, T=S=2048, G=1, I=2, M=16.
// out[n,t,s] = sum_m x[m,t,s]*wq[t][m][n]
//            + sum_i kw2[s,i,n] * (sum_m x[m,t,s]*kw1[s,i,m])
//            + x[n,t,s]*kdd[s,n]
//
// R12 = R11 with ONE change: input x loads are NON-TEMPORAL. The input is
// read exactly once per dispatch (zero reuse), but it was polluting L3 and
// evicting the output (which is exactly L3-sized, 256 MiB, and rewritten
// every replay). NT input loads let the output stay L3-resident: WRITE_SIZE
// should collapse from 268 MB to <100 MB. If WRITE stays 268, the ~2.5 TB/s
// pattern ceiling is confirmed as the roofline.

#define TDIM 2048
#define SDIM 2048
#define TT 8
#define SBLK 256
#define THREADS 512

typedef float vf4 __attribute__((ext_vector_type(4)));

__device__ __forceinline__ void barrier_nodrain() {
  asm volatile("s_waitcnt lgkmcnt(0)" ::: "memory");
  __builtin_amdgcn_s_barrier();
  asm volatile("" ::: "memory");
}

// Opaque pin: keeps loaded weights register-resident (R8: ~7% win).
__device__ __forceinline__ void pin4(vf4& v) {
  float a = v.x, b = v.y, c = v.z, d = v.w;
  asm volatile("" : "+v"(a), "+v"(b), "+v"(c), "+v"(d));
  v.x = a; v.y = b; v.z = c; v.w = d;
}

// ---- prep: transpose per-s weights to s-minor for coalesced reads ----
__global__ void chp_prep(const float* __restrict__ kw1, const float* __restrict__ kw2,
                         const float* __restrict__ kdd,
                         float* __restrict__ kt1, float* __restrict__ kt2,
                         float* __restrict__ kddt) {
  int tid = blockIdx.x * blockDim.x + threadIdx.x;  // 0 .. 163839
  if (tid < 65536) {
    int im = tid >> 11, s = tid & 2047;
    kt1[tid] = kw1[s * 32 + im];
  } else if (tid < 131072) {
    int v = tid - 65536;
    int im = v >> 11, s = v & 2047;
    kt2[v] = kw2[s * 32 + im];
  } else if (tid < 163840) {
    int v = tid - 131072;
    int n = v >> 11, s = v & 2047;
    kddt[v] = kdd[s * 16 + n];
  }
}

__device__ __forceinline__ vf4 ld4(const float* p) {
  return *reinterpret_cast<const vf4*>(p);
}
// Non-temporal load: bypass cache for the single-use input stream.
__device__ __forceinline__ vf4 ld4nt(const float* p) {
  return __builtin_nontemporal_load(reinterpret_cast<const vf4*>(p));
}
__device__ __forceinline__ void fma4(vf4& d, const vf4& a, const vf4& b) {
  d.x = fmaf(a.x, b.x, d.x); d.y = fmaf(a.y, b.y, d.y);
  d.z = fmaf(a.z, b.z, d.z); d.w = fmaf(a.w, b.w, d.w);
}
__device__ __forceinline__ void fma4s(vf4& d, const vf4& a, float b) {
  d.x = fmaf(a.x, b, d.x); d.y = fmaf(a.y, b, d.y);
  d.z = fmaf(a.z, b, d.z); d.w = fmaf(a.w, b, d.w);
}

template <bool KT>
__global__ __launch_bounds__(THREADS, 4) void chp_main(
    const float* __restrict__ in, const float* __restrict__ w,
    const float* __restrict__ qw1, const float* __restrict__ qw2,
    const float* __restrict__ qdd, const float* __restrict__ kw1,
    const float* __restrict__ kw2, const float* __restrict__ kdd,
    const float* __restrict__ kt1, const float* __restrict__ kt2,
    const float* __restrict__ kddt, float* __restrict__ out) {
  // x_lds[buf][m][quad], rows padded to 65 quads.
  __shared__ vf4 x_lds[2][16][65];
  __shared__ float wq_lds[2][256];

  const int tid = threadIdx.x;
  const int wv = tid >> 6;
  const int lane = tid & 63;
  const int j = lane & 7;        // owns rows {2j, 2j+1}
  const int qg = lane >> 3;      // quad within wave: 0..7
  const int quad = wv * 8 + qg;  // quad within block: 0..63
  const int s0 = blockIdx.x * SBLK + quad * 4;
  const int t0 = blockIdx.y * TT;

  // ---- per-thread register weights (own 2 rows, own s-quad), loaded ONCE ----
  vf4 kt1v[2][2], kt2v[2][2], kdv[2];
  if constexpr (KT) {
#pragma unroll
    for (int i = 0; i < 2; ++i)
#pragma unroll
      for (int k = 0; k < 2; ++k) {
        kt1v[i][k] = ld4(kt1 + (size_t)(i * 16 + 2 * j + k) * SDIM + s0);
        kt2v[i][k] = ld4(kt2 + (size_t)(i * 16 + 2 * j + k) * SDIM + s0);
      }
#pragma unroll
    for (int k = 0; k < 2; ++k) kdv[k] = ld4(kddt + (size_t)(2 * j + k) * SDIM + s0);
  } else {
#pragma unroll
    for (int i = 0; i < 2; ++i)
#pragma unroll
      for (int k = 0; k < 2; ++k)
#pragma unroll
        for (int c = 0; c < 4; ++c) {
          kt1v[i][k][c] = kw1[(size_t)(s0 + c) * 32 + i * 16 + 2 * j + k];
          kt2v[i][k][c] = kw2[(size_t)(s0 + c) * 32 + i * 16 + 2 * j + k];
        }
#pragma unroll
    for (int k = 0; k < 2; ++k)
#pragma unroll
      for (int c = 0; c < 4; ++c) kdv[k][c] = kdd[(size_t)(s0 + c) * 16 + 2 * j + k];
  }
#pragma unroll
  for (int i = 0; i < 2; ++i)
#pragma unroll
    for (int k = 0; k < 2; ++k) { pin4(kt1v[i][k]); pin4(kt2v[i][k]); }
#pragma unroll
  for (int k = 0; k < 2; ++k) pin4(kdv[k]);

  // wq-build: waves 0-3 (tid<256) build the 256 entries; wave-uniform branch.
  const bool builder = (tid < 256);
  const int bm = (tid >> 4) & 15, bn = tid & 15;
  const float wbase = builder ? w[bm * 16 + bn] : 0.0f;

  vf4 xp[2];
  float q1a = 0.f, q1b = 0.f, q2a = 0.f, q2b = 0.f, qd = 0.f;

  auto prefetch = [&](int t) {
#pragma unroll
    for (int k = 0; k < 2; ++k)
      xp[k] = ld4nt(in + ((size_t)(2 * j + k) * TDIM + t) * SDIM + s0);
    if (builder) {
      q1a = qw1[t * 32 + bm];
      q1b = qw1[t * 32 + 16 + bm];
      q2a = qw2[t * 32 + bn];
      q2b = qw2[t * 32 + 16 + bn];
      qd = qdd[t * 16 + bn];
    }
  };
  auto stage = [&](int buf) {
#pragma unroll
    for (int k = 0; k < 2; ++k) x_lds[buf][2 * j + k][quad] = xp[k];
    if (builder) {
      float v = fmaf(q1a, q2a, fmaf(q1b, q2b, wbase));
      if (bm == bn) v += 1.0f + qd;
      wq_lds[buf][tid] = v;
    }
  };

  // ---- prologue: prefetch + stage t0, prefetch t0+1 ----
  prefetch(t0);
  stage(0);
  prefetch(t0 + 1);
  barrier_nodrain();

  int cur = 0;
  for (int tt = 0; tt < TT; ++tt) {
    const int t = t0 + tt;
    const int nxt = cur ^ 1;

    // ---- compute t from LDS buf[cur] ----
    vf4 acc[2];
    vf4 p0 = (vf4){0.f, 0.f, 0.f, 0.f}, p1 = p0;
    acc[0] = (vf4){0.f, 0.f, 0.f, 0.f};
    acc[1] = (vf4){0.f, 0.f, 0.f, 0.f};

#pragma unroll
    for (int m = 0; m < 16; ++m) {
      const vf4 xm = x_lds[cur][m][quad];
      const float* wp = &wq_lds[cur][m * 16 + 2 * j];
      fma4s(acc[0], xm, wp[0]);
      fma4s(acc[1], xm, wp[1]);
      if ((m >> 1) == j) {  // own rows: hk partials + k-diag
        const int k = m & 1;
        fma4(p0, xm, kt1v[0][k]);
        fma4(p1, xm, kt1v[1][k]);
        fma4(acc[k], xm, kdv[k]);
      }
    }
    // butterfly over the 8 j-lanes (same qg): full hk at every lane
#pragma unroll
    for (int mask = 1; mask <= 4; mask <<= 1) {
      p0.x += __shfl_xor(p0.x, mask); p0.y += __shfl_xor(p0.y, mask);
      p0.z += __shfl_xor(p0.z, mask); p0.w += __shfl_xor(p0.w, mask);
      p1.x += __shfl_xor(p1.x, mask); p1.y += __shfl_xor(p1.y, mask);
      p1.z += __shfl_xor(p1.z, mask); p1.w += __shfl_xor(p1.w, mask);
    }
    // epilogue + stores (regular stores: output should stay L3-resident)
#pragma unroll
    for (int r = 0; r < 2; ++r) {
      fma4(acc[r], p0, kt2v[0][r]);
      fma4(acc[r], p1, kt2v[1][r]);
      *reinterpret_cast<vf4*>(out + ((size_t)(2 * j + r) * TDIM + t) * SDIM + s0) =
          acc[r];
    }

    // ---- stage t+1 into buf[nxt], then prefetch t+2 ----
    if (tt + 1 < TT) {
      stage(nxt);
      if (tt + 2 < TT) prefetch(t + 2);
    }
    // DS handoff drained; global prefetch stays in flight.
    barrier_nodrain();
    cur = nxt;
  }
}

extern "C" void kernel_launch(void* const* d_in, const int* in_sizes, int n_in,
                              void* d_out, int out_size, void* d_ws, size_t ws_size,
                              hipStream_t stream) {
  const float* in = (const float*)d_in[0];
  const float* qw1 = (const float*)d_in[1];
  const float* qw2 = (const float*)d_in[2];
  const float* kw1 = (const float*)d_in[3];
  const float* kw2 = (const float*)d_in[4];
  const float* qdd = (const float*)d_in[5];
  const float* kdd = (const float*)d_in[6];
  const float* w = (const float*)d_in[7];
  float* out = (float*)d_out;
  float* ws = (float*)d_ws;

  const bool useKT = (ws_size >= 163840ull * sizeof(float));
  float* kt1 = ws;
  float* kt2 = ws + 65536;
  float* kddt = ws + 131072;

  dim3 grid(SDIM / SBLK, TDIM / TT);  // (8, 256) = 2048 blocks
  if (useKT) {
    hipLaunchKernelGGL(chp_prep, dim3(640), dim3(256), 0, stream, kw1, kw2, kdd, kt1,
                       kt2, kddt);
    hipLaunchKernelGGL((chp_main<true>), grid, dim3(THREADS), 0, stream, in, w, qw1,
                       qw2, qdd, kw1, kw2, kdd, kt1, kt2, kddt, out);
  } else {
    hipLaunchKernelGGL((chp_main<false>), grid, dim3(THREADS), 0, stream, in, w, qw1,
                       qw2, qdd, kw1, kw2, kdd, nullptr, nullptr, nullptr, out);
  }
}